// Round 1
// baseline (2306.786 us; speedup 1.0000x reference)
//
#include <hip/hip_runtime.h>
#include <math.h>

#define NB 2
#define NC 64
#define NCQ 16
#define ND 96
#define NHW 9216            // 96*96
#define HWD (NHW * ND)      // 884736
#define CHWD (NC * HWD)     // 56623104
#define POS_PER_BLOCK 36
#define NCHUNK (NHW / POS_PER_BLOCK)   // 256

// ---------------------------------------------------------------------------
// Kernel 1: energy[b][d][e] = sum_{cq,hw} q[b,cq,hw,d] * k[b,cq,hw,e]
// q = Wq x + bq, k = Wk x + bk (1x1x1 conv = channel mix)
// ---------------------------------------------------------------------------
__global__ __launch_bounds__(256) void k_energy(
    const float* __restrict__ x,
    const float* __restrict__ Wq, const float* __restrict__ bq,
    const float* __restrict__ Wk, const float* __restrict__ bk,
    float* __restrict__ energy)
{
    __shared__ float xs[NC][ND + 1];      // [c][d], stride 97 (conflict-free cols)
    __shared__ float qs[NCQ][ND];         // [cq][d]
    __shared__ float ks[NCQ][ND];
    __shared__ float Wq_t[NC][NCQ];       // [c][cq] (rows of 16 floats, 16B aligned)
    __shared__ float Wk_t[NC][NCQ];

    const int t = threadIdx.x;
    const int b = blockIdx.x / NCHUNK;
    const int chunk = blockIdx.x % NCHUNK;

    for (int idx = t; idx < NC * NCQ; idx += 256) {
        int c = idx / NCQ, cq = idx % NCQ;
        Wq_t[c][cq] = Wq[cq * NC + c];
        Wk_t[c][cq] = Wk[cq * NC + c];
    }

    // per-thread 6x6 energy tile
    const int d0 = (t % 16) * 6;
    const int e0 = (t / 16) * 6;
    float acc[6][6];
#pragma unroll
    for (int i = 0; i < 6; ++i)
#pragma unroll
        for (int j = 0; j < 6; ++j) acc[i][j] = 0.f;

    const float* xb = x + b * CHWD;
    const int qk_which = t / 96;   // 0 = q, 1 = k, (t>=192 idle in qk phase)
    const int qk_d = t % 96;

    for (int it = 0; it < POS_PER_BLOCK; ++it) {
        const int hw = chunk * POS_PER_BLOCK + it;
        __syncthreads();  // protect xs/qs vs previous iteration readers
        // stage x slab: rows of 96 contiguous floats per channel
        for (int idx = t; idx < NC * ND; idx += 256) {
            int c = idx / ND, dd = idx % ND;
            xs[c][dd] = xb[c * HWD + hw * ND + dd];
        }
        __syncthreads();
        // q/k: one d-column per thread (threads 0..191)
        if (t < 192) {
            float a[NCQ];
#pragma unroll
            for (int cq = 0; cq < NCQ; ++cq) a[cq] = 0.f;
            const float(*Wt)[NCQ] = qk_which ? Wk_t : Wq_t;
            for (int c = 0; c < NC; ++c) {
                float xv = xs[c][qk_d];
                const float4* w4 = (const float4*)(&Wt[c][0]);
                float4 w0 = w4[0], w1 = w4[1], w2 = w4[2], w3 = w4[3];
                a[0] = fmaf(w0.x, xv, a[0]);  a[1] = fmaf(w0.y, xv, a[1]);
                a[2] = fmaf(w0.z, xv, a[2]);  a[3] = fmaf(w0.w, xv, a[3]);
                a[4] = fmaf(w1.x, xv, a[4]);  a[5] = fmaf(w1.y, xv, a[5]);
                a[6] = fmaf(w1.z, xv, a[6]);  a[7] = fmaf(w1.w, xv, a[7]);
                a[8] = fmaf(w2.x, xv, a[8]);  a[9] = fmaf(w2.y, xv, a[9]);
                a[10] = fmaf(w2.z, xv, a[10]); a[11] = fmaf(w2.w, xv, a[11]);
                a[12] = fmaf(w3.x, xv, a[12]); a[13] = fmaf(w3.y, xv, a[13]);
                a[14] = fmaf(w3.z, xv, a[14]); a[15] = fmaf(w3.w, xv, a[15]);
            }
            if (qk_which == 0) {
#pragma unroll
                for (int cq = 0; cq < NCQ; ++cq) qs[cq][qk_d] = a[cq] + bq[cq];
            } else {
#pragma unroll
                for (int cq = 0; cq < NCQ; ++cq) ks[cq][qk_d] = a[cq] + bk[cq];
            }
        }
        __syncthreads();
        // energy rank-16 update on the 6x6 tile
#pragma unroll
        for (int cq = 0; cq < NCQ; ++cq) {
            float qv[6], kv[6];
#pragma unroll
            for (int i = 0; i < 6; ++i) qv[i] = qs[cq][d0 + i];
#pragma unroll
            for (int j = 0; j < 6; ++j) kv[j] = ks[cq][e0 + j];
#pragma unroll
            for (int i = 0; i < 6; ++i)
#pragma unroll
                for (int j = 0; j < 6; ++j)
                    acc[i][j] = fmaf(qv[i], kv[j], acc[i][j]);
        }
    }

    float* eb = energy + b * ND * ND;
#pragma unroll
    for (int i = 0; i < 6; ++i)
#pragma unroll
        for (int j = 0; j < 6; ++j)
            atomicAdd(&eb[(d0 + i) * ND + (e0 + j)], acc[i][j]);
}

// ---------------------------------------------------------------------------
// Kernel 2: softmax over last axis of energy (192 rows of 96)
// ---------------------------------------------------------------------------
__global__ __launch_bounds__(128) void k_softmax(
    const float* __restrict__ energy, float* __restrict__ attn)
{
    const int row = blockIdx.x;      // b*96 + d
    const int t = threadIdx.x;
    __shared__ float red[4];

    float v = (t < ND) ? energy[row * ND + t] : -INFINITY;
    float m = v;
#pragma unroll
    for (int o = 32; o > 0; o >>= 1) m = fmaxf(m, __shfl_down(m, o));
    if ((t & 63) == 0) red[t >> 6] = m;
    __syncthreads();
    const float gm = fmaxf(red[0], red[1]);
    float ev = (t < ND) ? __expf(v - gm) : 0.f;
    float s = ev;
#pragma unroll
    for (int o = 32; o > 0; o >>= 1) s += __shfl_down(s, o);
    if ((t & 63) == 0) red[2 + (t >> 6)] = s;
    __syncthreads();
    const float gs = red[2] + red[3];
    if (t < ND) attn[row * ND + t] = ev / gs;
}

// ---------------------------------------------------------------------------
// Kernel 3: out[b,co,hw,d] = gamma*( sum_c Wv[co,c]*ys[c] + bv[co] ) + x[b,co,hw,d]
//           ys[c] = sum_e x[b,c,hw,e] * attn[b,d,e]
// Thread = (position p in {0,1}, d). ys[64] in registers.
// ---------------------------------------------------------------------------
__global__ __launch_bounds__(192, 2) void k_out(
    const float* __restrict__ x,
    const float* __restrict__ Wv, const float* __restrict__ bv,
    const float* __restrict__ attn, const float* __restrict__ gamma,
    float* __restrict__ out)
{
    __shared__ float xs[2][ND][NC];   // [p][e][c] — phase-A reads are wave-uniform

    const int t = threadIdx.x;
    const int b = blockIdx.x / NCHUNK;
    const int chunk = blockIdx.x % NCHUNK;
    const int p = t / 96;
    const int d = t % 96;
    const float g = gamma[0];

    const float* xb = x + b * CHWD;
    float* ob = out + b * CHWD;
    const float* attn_row = attn + (b * ND + d) * ND;

    const int cl = t & 63;     // staging: lane -> channel (LDS writes conflict-free)
    const int slot = t >> 6;   // 0..2

    for (int it = 0; it < POS_PER_BLOCK / 2; ++it) {
        const int hw0 = chunk * POS_PER_BLOCK + it * 2;
        __syncthreads();
        // stage 2 positions, transposed: xs[p][d][c] = x[c][hw0+p][d]
#pragma unroll 2
        for (int i = 0; i < 64; ++i) {
            int pd = slot * 64 + i;
            int pp = pd / 96, dd = pd % 96;
            xs[pp][dd][cl] = xb[cl * HWD + (hw0 + pp) * ND + dd];
        }
        __syncthreads();

        // phase A: ys[c] = sum_e xs[p][e][c] * attn[d][e]
        float ys[NC];
#pragma unroll
        for (int c = 0; c < NC; ++c) ys[c] = 0.f;

        for (int e8 = 0; e8 < ND; e8 += 8) {   // 12 iterations, rolled
            float4 a0 = *(const float4*)(attn_row + e8);
            float4 a1 = *(const float4*)(attn_row + e8 + 4);
            float av[8] = {a0.x, a0.y, a0.z, a0.w, a1.x, a1.y, a1.z, a1.w};
#pragma unroll
            for (int j = 0; j < 8; ++j) {
                const float4* xrow = (const float4*)(&xs[p][e8 + j][0]);
                const float aj = av[j];
#pragma unroll
                for (int cb = 0; cb < 16; ++cb) {
                    float4 xv = xrow[cb];
                    ys[4 * cb + 0] = fmaf(xv.x, aj, ys[4 * cb + 0]);
                    ys[4 * cb + 1] = fmaf(xv.y, aj, ys[4 * cb + 1]);
                    ys[4 * cb + 2] = fmaf(xv.z, aj, ys[4 * cb + 2]);
                    ys[4 * cb + 3] = fmaf(xv.w, aj, ys[4 * cb + 3]);
                }
            }
        }

        // phase B: channel mix + bias + residual, 4 output channels at a time
        const int hw = hw0 + p;
        const int base = hw * ND + d;
        for (int co = 0; co < NC; co += 4) {
            float s0 = bv[co + 0], s1 = bv[co + 1], s2 = bv[co + 2], s3 = bv[co + 3];
#pragma unroll
            for (int c = 0; c < NC; c += 4) {
                float4 w0 = *(const float4*)(Wv + (co + 0) * NC + c);
                float4 w1 = *(const float4*)(Wv + (co + 1) * NC + c);
                float4 w2 = *(const float4*)(Wv + (co + 2) * NC + c);
                float4 w3 = *(const float4*)(Wv + (co + 3) * NC + c);
                float y0 = ys[c], y1 = ys[c + 1], y2 = ys[c + 2], y3 = ys[c + 3];
                s0 = fmaf(w0.x, y0, fmaf(w0.y, y1, fmaf(w0.z, y2, fmaf(w0.w, y3, s0))));
                s1 = fmaf(w1.x, y0, fmaf(w1.y, y1, fmaf(w1.z, y2, fmaf(w1.w, y3, s1))));
                s2 = fmaf(w2.x, y0, fmaf(w2.y, y1, fmaf(w2.z, y2, fmaf(w2.w, y3, s2))));
                s3 = fmaf(w3.x, y0, fmaf(w3.y, y1, fmaf(w3.z, y2, fmaf(w3.w, y3, s3))));
            }
            ob[(co + 0) * HWD + base] = fmaf(g, s0, xb[(co + 0) * HWD + base]);
            ob[(co + 1) * HWD + base] = fmaf(g, s1, xb[(co + 1) * HWD + base]);
            ob[(co + 2) * HWD + base] = fmaf(g, s2, xb[(co + 2) * HWD + base]);
            ob[(co + 3) * HWD + base] = fmaf(g, s3, xb[(co + 3) * HWD + base]);
        }
    }
}

// ---------------------------------------------------------------------------
extern "C" void kernel_launch(void* const* d_in, const int* in_sizes, int n_in,
                              void* d_out, int out_size, void* d_ws, size_t ws_size,
                              hipStream_t stream)
{
    const float* x     = (const float*)d_in[0];
    const float* Wq    = (const float*)d_in[1];
    const float* bq    = (const float*)d_in[2];
    const float* Wk    = (const float*)d_in[3];
    const float* bk    = (const float*)d_in[4];
    const float* Wv    = (const float*)d_in[5];
    const float* bv    = (const float*)d_in[6];
    const float* gamma = (const float*)d_in[7];

    float* energy = (float*)d_ws;                  // 2*96*96 floats
    float* attn   = energy + NB * ND * ND;         // 2*96*96 floats

    hipMemsetAsync(energy, 0, NB * ND * ND * sizeof(float), stream);
    k_energy<<<NB * NCHUNK, 256, 0, stream>>>(x, Wq, bq, Wk, bk, energy);
    k_softmax<<<NB * ND, 128, 0, stream>>>(energy, attn);
    k_out<<<NB * NCHUNK, 192, 0, stream>>>(x, Wv, bv, attn, gamma, (float*)d_out);
}